// Round 12
// baseline (358.054 us; speedup 1.0000x reference)
//
#include <hip/hip_runtime.h>
#include <hip/hip_bf16.h>
#include <math.h>

#define N_NODES 20000
#define E2      240000     // directed edges (2E)
#define EP      120000     // positive edges
#define ENEG    600000     // negative edges
#define ETOT    720000     // EP + ENEG
#define NTILE   11250      // ETOT / 64
#define EMLP_BLOCKS 1024   // persistent: 4 blocks/CU

// merged-kernel block ranges
#define WA_B  64
#define W1T_B 256
#define WML_B 128
#define UV_B  2813
#define HA_B  938
#define HP_B  469
#define FA_B  938
#define FP_B  469
#define DIS_B 79

typedef __attribute__((ext_vector_type(8))) short bf16x8;
typedef __attribute__((ext_vector_type(4))) float f32x4;

__device__ __forceinline__ float logsigf(float x) {
    return fminf(x, 0.0f) - log1pf(expf(-fabsf(x)));
}

__device__ __forceinline__ unsigned short f2bf(float f) {
    unsigned u = __float_as_uint(f);
    u += 0x7FFF + ((u >> 16) & 1);   // RNE
    return (unsigned short)(u >> 16);
}

__device__ __forceinline__ float bflo(unsigned u) { return __uint_as_float(u << 16); }
__device__ __forceinline__ float bfhi(unsigned u) { return __uint_as_float(u & 0xFFFF0000u); }

__device__ __forceinline__ void store_out(float v, float* p) { *p = v; }
__device__ __forceinline__ void store_out(float v, unsigned short* p) { *p = f2bf(v); }
__device__ __forceinline__ float load_in(const float* p) { return *p; }
__device__ __forceinline__ float load_in(const unsigned short* p) {
    return __uint_as_float(((unsigned)*p) << 16);
}

// pack 2 dims of hu/hv into k'-layout: [u(d0)|v(d0), bf2(ad0,pr0), u(d1)|v(d1), bf2(ad1,pr1)]
__device__ __forceinline__ int4 pack_phi(unsigned hu, unsigned hv) {
    const float fu0 = __uint_as_float(hu << 16);
    const float fu1 = __uint_as_float(hu & 0xFFFF0000u);
    const float fv0 = __uint_as_float(hv << 16);
    const float fv1 = __uint_as_float(hv & 0xFFFF0000u);
    const float ad0 = fabsf(fu0 - fv0), ad1 = fabsf(fu1 - fv1);
    const float pr0 = fu0 * fv0,        pr1 = fu1 * fv1;
    union { __hip_bfloat162 h; int u; } c0, c1;
    c0.h = __float22bfloat162_rn(float2{ad0, pr0});
    c1.h = __float22bfloat162_rn(float2{ad1, pr1});
    int4 r;
    r.x = (int)((hu & 0xFFFFu) | (hv << 16));
    r.y = c0.u;
    r.z = (int)((hu >> 16) | (hv & 0xFFFF0000u));
    r.w = c1.u;
    return r;
}

// --- merged prep: WaT + W1T + WmlT permutes, uv build, both CSR histograms ---
__global__ void k_prep_csr(const float* __restrict__ Wa, unsigned short* __restrict__ WaT,
                           const float* __restrict__ W1, unsigned short* __restrict__ W1T,
                           const float* __restrict__ Wmu, const float* __restrict__ Wlv,
                           unsigned short* __restrict__ WmlT,
                           const int* __restrict__ pos, const int* __restrict__ neg,
                           int2* __restrict__ uv,
                           const int* __restrict__ e_dst, int* __restrict__ cntA,
                           const int* __restrict__ pd, int* __restrict__ cntP) {
    const int b = blockIdx.x, tid = threadIdx.x;
    if (b < WA_B) {
        const int idx = b * 256 + tid;
        const int n = idx >> 8, kp = idx & 255;
        const int d = kp >> 2, part = kp & 3;
        WaT[idx] = f2bf(Wa[(part * 64 + d) * 64 + n]);
    } else if (b < WA_B + W1T_B) {
        const int idx = (b - WA_B) * 256 + tid;            // 0..65535
        const int n = idx >> 8, k = idx & 255;
        W1T[idx] = f2bf(W1[k * 256 + n]);
    } else if (b < WA_B + W1T_B + WML_B) {
        const int idx = (b - WA_B - W1T_B) * 256 + tid;    // 0..32767
        const int n = idx >> 8, k = idx & 255;             // n: interleaved col
        const float* W = (n & 1) ? Wlv : Wmu;
        WmlT[idx] = f2bf(W[k * 64 + (n >> 1)]);
    } else if (b < WA_B + W1T_B + WML_B + UV_B) {
        const int j = (b - WA_B - W1T_B - WML_B) * 256 + tid;
        if (j < ETOT) {
            int u, v;
            if (j < EP) { u = pos[j]; v = pos[EP + j]; }
            else        { u = neg[j - EP]; v = neg[ENEG + (j - EP)]; }
            uv[j] = make_int2(u, v);
        }
    } else if (b < WA_B + W1T_B + WML_B + UV_B + HA_B) {
        const int e = (b - WA_B - W1T_B - WML_B - UV_B) * 256 + tid;
        if (e < E2) atomicAdd(&cntA[e_dst[e]], 1);
    } else {
        const int e = (b - WA_B - W1T_B - WML_B - UV_B - HA_B) * 256 + tid;
        if (e < EP) atomicAdd(&cntP[pd[e]], 1);
    }
}

// ---- both exclusive scans in one launch: block 0 -> graph A, block 1 -> P ----
__global__ __launch_bounds__(1024) void k_scan2(int* __restrict__ cntA, int* __restrict__ rsA,
                                                int* __restrict__ cntP, int* __restrict__ rsP) {
    int* cnt = blockIdx.x ? cntP : cntA;
    int* rs  = blockIdx.x ? rsP  : rsA;
    int* cur = cnt;   // cursor aliases cnt (read-before-overwrite)
    const int n = N_NODES;
    __shared__ int wexc[16];
    __shared__ int s_carry, s_tot;
    const int tid = threadIdx.x, lane = tid & 63, wid = tid >> 6;
    if (tid == 0) s_carry = 0;
    __syncthreads();
    for (int base = 0; base < n; base += 1024) {
        const int i = base + tid;
        const int v = (i < n) ? cnt[i] : 0;
        int x = v;
#pragma unroll
        for (int d = 1; d < 64; d <<= 1) {
            const int t = __shfl_up(x, d, 64);
            if (lane >= d) x += t;
        }
        if (lane == 63) wexc[wid] = x;
        __syncthreads();
        if (tid == 0) {
            int a = 0;
#pragma unroll
            for (int k = 0; k < 16; ++k) { const int t = wexc[k]; wexc[k] = a; a += t; }
            s_tot = a;
        }
        __syncthreads();
        const int excl = s_carry + wexc[wid] + x - v;
        if (i < n) { rs[i] = excl; cur[i] = excl; }
        __syncthreads();
        if (tid == 0) s_carry += s_tot;
        __syncthreads();
    }
    if (tid == 0) rs[n] = s_carry;
}

// ---- merged finish: fill both adjacency lists + dis ----
__global__ void k_finish_csr(const int* __restrict__ e_src, const int* __restrict__ e_dst,
                             int* __restrict__ curA, int* __restrict__ adjA,
                             const int* __restrict__ ps, const int* __restrict__ pd,
                             int* __restrict__ curP, int* __restrict__ adjP,
                             const int* __restrict__ rsP, float* __restrict__ dis) {
    const int b = blockIdx.x, tid = threadIdx.x;
    if (b < FA_B) {
        const int e = b * 256 + tid;
        if (e < E2) {
            const int p = atomicAdd(&curA[e_dst[e]], 1);
            adjA[p] = e_src[e];
        }
    } else if (b < FA_B + FP_B) {
        const int e = (b - FA_B) * 256 + tid;
        if (e < EP) {
            const int p = atomicAdd(&curP[pd[e]], 1);
            adjP[p] = ps[e];
        }
    } else {
        const int i = (b - FA_B - FP_B) * 256 + tid;
        if (i < N_NODES) dis[i] = rsqrtf((float)(rsP[i + 1] - rsP[i] + 1));
    }
}

// ---- K1: m1bf = bf16(x @ W1) via MFMA. grid 625x4: 32-row M x 64-col N ----
__global__ __launch_bounds__(256) void k_mm_xW1_mfma(const float* __restrict__ x,
                                                     const unsigned short* __restrict__ W1T,
                                                     unsigned short* __restrict__ m1) {
    __shared__ unsigned short sA[32 * 264];   // 16896 B
    const int tid = threadIdx.x;
    const int w = tid >> 6, lane = tid & 63;
    const int l15 = lane & 15, quad = lane >> 4;
    const int mb = blockIdx.x >> 2, nb = blockIdx.x & 3;

    // stage A: 32 rows x 256 k, fp32 -> bf16
    for (int i = tid; i < 2048; i += 256) {
        const int row = i >> 6, kc = (i & 63) << 2;
        const float4 xv = *(const float4*)&x[((long)mb * 32 + row) * 256 + kc];
        union { unsigned short s[4]; unsigned long long ll; } pk;
        pk.s[0] = f2bf(xv.x); pk.s[1] = f2bf(xv.y);
        pk.s[2] = f2bf(xv.z); pk.s[3] = f2bf(xv.w);
        *(unsigned long long*)&sA[row * 264 + kc] = pk.ll;
    }

    bf16x8 breg[8];
#pragma unroll
    for (int ks = 0; ks < 8; ++ks)
        breg[ks] = *(const bf16x8*)&W1T[((nb * 64 + w * 16 + l15) << 8) + ks * 32 + quad * 8];
    __syncthreads();

    f32x4 acc[2];
    acc[0] = (f32x4){0.f,0.f,0.f,0.f};
    acc[1] = (f32x4){0.f,0.f,0.f,0.f};
#pragma unroll
    for (int ks = 0; ks < 8; ++ks) {
#pragma unroll
        for (int st = 0; st < 2; ++st) {
            const bf16x8 af = *(const bf16x8*)&sA[(st * 16 + l15) * 264 + ks * 32 + quad * 8];
            acc[st] = __builtin_amdgcn_mfma_f32_16x16x32_bf16(af, breg[ks], acc[st], 0, 0, 0);
        }
    }
    // D: row = quad*4+r (x-row), col = l15 (n)
#pragma unroll
    for (int st = 0; st < 2; ++st)
#pragma unroll
        for (int r = 0; r < 4; ++r)
            m1[((long)mb * 32 + st * 16 + quad * 4 + r) * 256 + nb * 64 + w * 16 + l15] =
                f2bf(acc[st][r]);
}

// ---- K2: h1bf = bf16(relu(LN(segsum(m1bf[adj]) + b1))); gather dim 256 ----
__global__ __launch_bounds__(256) void k_gather_ln(const unsigned short* __restrict__ m1,
                                                   const int* __restrict__ rs,
                                                   const int* __restrict__ adj,
                                                   const float* __restrict__ b1,
                                                   const float* __restrict__ g1,
                                                   const float* __restrict__ bt1,
                                                   unsigned short* __restrict__ h1) {
    const int wid = threadIdx.x >> 6, lane = threadIdx.x & 63;
    const int n = blockIdx.x * 4 + wid;
    const int beg = rs[n], end = rs[n + 1];
    float4 a0 = {0.f,0.f,0.f,0.f}, a1 = {0.f,0.f,0.f,0.f};
    int j = beg;
    for (; j + 1 < end; j += 2) {
        const int s0 = adj[j], s1 = adj[j + 1];
        const uint2 u = *(const uint2*)(m1 + (long)s0 * 256 + lane * 4);
        const uint2 v = *(const uint2*)(m1 + (long)s1 * 256 + lane * 4);
        a0.x += bflo(u.x); a0.y += bfhi(u.x); a0.z += bflo(u.y); a0.w += bfhi(u.y);
        a1.x += bflo(v.x); a1.y += bfhi(v.x); a1.z += bflo(v.y); a1.w += bfhi(v.y);
    }
    if (j < end) {
        const int s0 = adj[j];
        const uint2 u = *(const uint2*)(m1 + (long)s0 * 256 + lane * 4);
        a0.x += bflo(u.x); a0.y += bfhi(u.x); a0.z += bflo(u.y); a0.w += bfhi(u.y);
    }
    float4 v;
    const float4 b = *(const float4*)(b1 + lane * 4);
    v.x = a0.x + a1.x + b.x; v.y = a0.y + a1.y + b.y;
    v.z = a0.z + a1.z + b.z; v.w = a0.w + a1.w + b.w;
    float s  = v.x + v.y + v.z + v.w;
    float sq = v.x * v.x + v.y * v.y + v.z * v.z + v.w * v.w;
    for (int o = 32; o > 0; o >>= 1) {
        s  += __shfl_xor(s, o, 64);
        sq += __shfl_xor(sq, o, 64);
    }
    const float mean = s * (1.0f / 256.0f);
    const float var  = sq * (1.0f / 256.0f) - mean * mean;
    const float rsv = rsqrtf(var + 1e-5f);
    const float4 g  = *(const float4*)(g1 + lane * 4);
    const float4 bt = *(const float4*)(bt1 + lane * 4);
    union { unsigned short sh[4]; unsigned long long ll; } pk;
    pk.sh[0] = f2bf(fmaxf((v.x - mean) * rsv * g.x + bt.x, 0.f));
    pk.sh[1] = f2bf(fmaxf((v.y - mean) * rsv * g.y + bt.y, 0.f));
    pk.sh[2] = f2bf(fmaxf((v.z - mean) * rsv * g.z + bt.z, 0.f));
    pk.sh[3] = f2bf(fmaxf((v.w - mean) * rsv * g.w + bt.w, 0.f));
    *(unsigned long long*)&h1[(long)n * 256 + lane * 4] = pk.ll;
}

// ---- K3: hmlbf = bf16(h1bf @ [Wmu|Wlv] interleaved) via MFMA. grid 625x2 ----
__global__ __launch_bounds__(256) void k_mm_hml_mfma(const unsigned short* __restrict__ h1,
                                                     const unsigned short* __restrict__ WmlT,
                                                     unsigned short* __restrict__ hml) {
    __shared__ unsigned short sA[32 * 264];
    const int tid = threadIdx.x;
    const int w = tid >> 6, lane = tid & 63;
    const int l15 = lane & 15, quad = lane >> 4;
    const int mb = blockIdx.x >> 1, nb = blockIdx.x & 1;

    // stage A: 32 rows x 32 chunks of 8 shorts (full 256-k rows)
    for (int i = tid; i < 1024; i += 256) {
        const int row = i >> 5, kc = (i & 31) << 3;
        *(int4*)&sA[row * 264 + kc] = *(const int4*)&h1[((long)mb * 32 + row) * 256 + kc];
    }

    bf16x8 breg[8];
#pragma unroll
    for (int ks = 0; ks < 8; ++ks)
        breg[ks] = *(const bf16x8*)&WmlT[((nb * 64 + w * 16 + l15) << 8) + ks * 32 + quad * 8];
    __syncthreads();

    f32x4 acc[2];
    acc[0] = (f32x4){0.f,0.f,0.f,0.f};
    acc[1] = (f32x4){0.f,0.f,0.f,0.f};
#pragma unroll
    for (int ks = 0; ks < 8; ++ks) {
#pragma unroll
        for (int st = 0; st < 2; ++st) {
            const bf16x8 af = *(const bf16x8*)&sA[(st * 16 + l15) * 264 + ks * 32 + quad * 8];
            acc[st] = __builtin_amdgcn_mfma_f32_16x16x32_bf16(af, breg[ks], acc[st], 0, 0, 0);
        }
    }
#pragma unroll
    for (int st = 0; st < 2; ++st)
#pragma unroll
        for (int r = 0; r < 4; ++r)
            hml[((long)mb * 32 + st * 16 + quad * 4 + r) * 128 + nb * 64 + w * 16 + l15] =
                f2bf(acc[st][r]);
}

// ---- K4: gather hmlbf (interleaved mu/lv) + z (bf16); kl partial -> array ----
__global__ __launch_bounds__(256) void k_gather_mulv(const unsigned short* __restrict__ hml,
                                                     const int* __restrict__ rs,
                                                     const int* __restrict__ adj,
                                                     const float* __restrict__ bmu,
                                                     const float* __restrict__ blv,
                                                     const float* __restrict__ eps,
                                                     unsigned short* __restrict__ z,
                                                     double* __restrict__ kl_part) {
    __shared__ double sKL[4];
    const int wid = threadIdx.x >> 6, lane = threadIdx.x & 63;
    const int n = blockIdx.x * 4 + wid;
    const int beg = rs[n], end = rs[n + 1];
    float amu0 = 0.f, amu1 = 0.f, alv0 = 0.f, alv1 = 0.f;
    int j = beg;
    for (; j + 1 < end; j += 2) {
        const int s0 = adj[j], s1 = adj[j + 1];
        const unsigned u0 = *(const unsigned*)(hml + (long)s0 * 128 + lane * 2);
        const unsigned u1 = *(const unsigned*)(hml + (long)s1 * 128 + lane * 2);
        amu0 += bflo(u0); alv0 += bfhi(u0);
        amu1 += bflo(u1); alv1 += bfhi(u1);
    }
    if (j < end) {
        const int s0 = adj[j];
        const unsigned u0 = *(const unsigned*)(hml + (long)s0 * 128 + lane * 2);
        amu0 += bflo(u0); alv0 += bfhi(u0);
    }
    const float mu = amu0 + amu1 + bmu[lane];
    const float lv = alv0 + alv1 + blv[lane];
    z[(long)n * 64 + lane] = f2bf(mu + eps[(long)n * 64 + lane] * expf(0.5f * lv));
    float term = 1.0f + lv - mu * mu - expf(lv);
    for (int o = 32; o > 0; o >>= 1) term += __shfl_xor(term, o, 64);
    if (lane == 0) sKL[wid] = (double)term;
    __syncthreads();
    if (threadIdx.x == 0)
        kl_part[blockIdx.x] = sKL[0] + sKL[1] + sKL[2] + sKL[3];
}

// ---- K5/K6: fused decoder layer: gather_norm + 64x64 matmul + relu ----
template <typename IN, typename OUT>
__global__ __launch_bounds__(256) void k_dec_fused(const IN* __restrict__ feat,
                                                   const int* __restrict__ rs,
                                                   const int* __restrict__ adj,
                                                   const float* __restrict__ dis,
                                                   const float* __restrict__ Wd,
                                                   const float* __restrict__ bd,
                                                   OUT* __restrict__ out) {
    __shared__ float sW[64 * 64];
    __shared__ float rows[4][64];
    const int tid = threadIdx.x;
    {
        const float4* w4 = (const float4*)Wd;
        float4* sw4 = (float4*)sW;
        for (int i = tid; i < 1024; i += 256) sw4[i] = w4[i];
    }
    const int wid = tid >> 6, lane = tid & 63;
    const int n = blockIdx.x * 4 + wid;
    const int beg = rs[n], end = rs[n + 1];
    float a0 = 0.f, a1 = 0.f;
    int j = beg;
    for (; j + 1 < end; j += 2) {
        const int s0 = adj[j], s1 = adj[j + 1];
        a0 += load_in(&feat[(long)s0 * 64 + lane]) * dis[s0];
        a1 += load_in(&feat[(long)s1 * 64 + lane]) * dis[s1];
    }
    if (j < end) {
        const int s0 = adj[j];
        a0 += load_in(&feat[(long)s0 * 64 + lane]) * dis[s0];
    }
    const float dn = dis[n];
    rows[wid][lane] = (a0 + a1) * dn + load_in(&feat[(long)n * 64 + lane]) * dn * dn;
    __syncthreads();
    float acc = 0.f;
    for (int k = 0; k < 64; k += 4) {
        const float4 a = *(const float4*)&rows[wid][k];
        acc += a.x * sW[(k+0)*64+lane] + a.y * sW[(k+1)*64+lane]
             + a.z * sW[(k+2)*64+lane] + a.w * sW[(k+3)*64+lane];
    }
    store_out(fmaxf(acc + bd[lane], 0.f), &out[(long)n * 64 + lane]);
}

// ---------------- K9: edge MLP, persistent MFMA, 2x2 wave tiling ----------------
// Wave w owns edge-half eh=w&1 (32 edges) x n-half nh=w>>1 (32 cols); B-frags
// for both 16-n tiles in 64 VGPRs. Each wave reads only ITS edge-half of sPhi:
// per-tile LDS reads halve vs full-tile scheme (128 -> 64 b128).
__global__ __launch_bounds__(256, 4) void k_edge_mlp_mfma(
        const unsigned short* __restrict__ h2bf,
        const int2* __restrict__ uv,
        const unsigned short* __restrict__ WaT,
        const float* __restrict__ ba,
        const float* __restrict__ Wb,
        const float* __restrict__ bb,
        const float* __restrict__ tau,
        double* __restrict__ recon_part) {
    __shared__ unsigned short sPhi[64 * 264];  // 33792 B
    __shared__ float sEp[128];                 // [wave][edge-in-half]
    __shared__ double sRed[4];
    const int tid = threadIdx.x;
    const int w = tid >> 6, lane = tid & 63;
    const int l15 = lane & 15, quad = lane >> 4;
    const int ge = lane >> 3;
    const int c  = lane & 7;
    const int eh = w & 1;      // edge-half this wave multiplies
    const int nh = w >> 1;     // n-half this wave owns

    bf16x8 breg[2][8];
#pragma unroll
    for (int nt = 0; nt < 2; ++nt)
#pragma unroll
        for (int ks = 0; ks < 8; ++ks)
            breg[nt][ks] = *(const bf16x8*)&WaT[(nh * 32 + nt * 16 + l15) * 256 +
                                                ks * 32 + quad * 8];

    float4 ba4[2], wb4[2];
#pragma unroll
    for (int nt = 0; nt < 2; ++nt) {
        ba4[nt] = *(const float4*)&ba[nh * 32 + nt * 16 + quad * 4];
        wb4[nt] = *(const float4*)&Wb[nh * 32 + nt * 16 + quad * 4];
    }
    const float bb0 = bb[0];
    const float itau = 1.0f / fmaxf(tau[0], 1e-4f);

    float lsum = 0.f;

    int t = blockIdx.x;
    int2 uv0 = uv[(long)t * 64 + w * 16 + ge];
    int2 uv1 = uv[(long)t * 64 + w * 16 + 8 + ge];
    int4 hu0 = *(const int4*)&h2bf[(long)uv0.x * 64 + c * 8];
    int4 hv0 = *(const int4*)&h2bf[(long)uv0.y * 64 + c * 8];
    int4 hu1 = *(const int4*)&h2bf[(long)uv1.x * 64 + c * 8];
    int4 hv1 = *(const int4*)&h2bf[(long)uv1.y * 64 + c * 8];

    for (; t < NTILE; t += EMLP_BLOCKS) {
        // pack this wave's 16 rows of phi (rows w*16..w*16+15, stride 264)
        {
            unsigned short* d0 = &sPhi[(w * 16 + ge) * 264 + c * 32];
            *(int4*)(d0 +  0) = pack_phi((unsigned)hu0.x, (unsigned)hv0.x);
            *(int4*)(d0 +  8) = pack_phi((unsigned)hu0.y, (unsigned)hv0.y);
            *(int4*)(d0 + 16) = pack_phi((unsigned)hu0.z, (unsigned)hv0.z);
            *(int4*)(d0 + 24) = pack_phi((unsigned)hu0.w, (unsigned)hv0.w);
            unsigned short* d1 = &sPhi[(w * 16 + 8 + ge) * 264 + c * 32];
            *(int4*)(d1 +  0) = pack_phi((unsigned)hu1.x, (unsigned)hv1.x);
            *(int4*)(d1 +  8) = pack_phi((unsigned)hu1.y, (unsigned)hv1.y);
            *(int4*)(d1 + 16) = pack_phi((unsigned)hu1.z, (unsigned)hv1.z);
            *(int4*)(d1 + 24) = pack_phi((unsigned)hu1.w, (unsigned)hv1.w);
        }
        __syncthreads();

        const int tn = t + EMLP_BLOCKS;
        if (tn < NTILE) {
            uv0 = uv[(long)tn * 64 + w * 16 + ge];
            uv1 = uv[(long)tn * 64 + w * 16 + 8 + ge];
            hu0 = *(const int4*)&h2bf[(long)uv0.x * 64 + c * 8];
            hv0 = *(const int4*)&h2bf[(long)uv0.y * 64 + c * 8];
            hu1 = *(const int4*)&h2bf[(long)uv1.x * 64 + c * 8];
            hv1 = *(const int4*)&h2bf[(long)uv1.y * 64 + c * 8];
        }

        // MFMA: D[n][edge]; A = breg n-slice, B = phi rows of THIS edge-half
        f32x4 acc[2][2];
#pragma unroll
        for (int mt = 0; mt < 2; ++mt)
#pragma unroll
            for (int nt = 0; nt < 2; ++nt) acc[mt][nt] = (f32x4){0.f, 0.f, 0.f, 0.f};
#pragma unroll
        for (int ks = 0; ks < 8; ++ks) {
#pragma unroll
            for (int mt = 0; mt < 2; ++mt) {
                const bf16x8 bf = *(const bf16x8*)&sPhi[(eh * 32 + mt * 16 + l15) * 264 +
                                                        ks * 32 + quad * 8];
#pragma unroll
                for (int nt = 0; nt < 2; ++nt)
                    acc[mt][nt] = __builtin_amdgcn_mfma_f32_16x16x32_bf16(
                        breg[nt][ks], bf, acc[mt][nt], 0, 0, 0);
            }
        }

        // epilogue: relu(+ba)*Wb over this wave's 32 n, 2 shuffles
        float sv[2];
#pragma unroll
        for (int mt = 0; mt < 2; ++mt) {
            float s = 0.f;
#pragma unroll
            for (int nt = 0; nt < 2; ++nt)
                s += fmaxf(acc[mt][nt][0] + ba4[nt].x, 0.f) * wb4[nt].x
                   + fmaxf(acc[mt][nt][1] + ba4[nt].y, 0.f) * wb4[nt].y
                   + fmaxf(acc[mt][nt][2] + ba4[nt].z, 0.f) * wb4[nt].z
                   + fmaxf(acc[mt][nt][3] + ba4[nt].w, 0.f) * wb4[nt].w;
            s += __shfl_xor(s, 16, 64);
            s += __shfl_xor(s, 32, 64);
            sv[mt] = s;   // edge eh*32 + mt*16 + l15, summed over 32 n of nh
        }
        if (lane < 32) sEp[w * 32 + lane] = (lane & 16) ? sv[1] : sv[0];
        __syncthreads();

        // wave w consumes tile-edges [w*16, w*16+16): halves combined from
        // waves {h, h+2} where h = e>>5
        if (lane < 16) {
            const int e = w * 16 + lane;
            const int h = e >> 5, e31 = e & 31;
            const float s_e = sEp[h * 32 + e31] + sEp[(h + 2) * 32 + e31];
            const long j = (long)t * 64 + e;
            const float logit = (s_e + bb0) * itau;
            lsum += (j < EP) ? 5.0f * logsigf(logit) : logsigf(-logit);
        }
    }

    for (int o = 32; o > 0; o >>= 1) lsum += __shfl_xor(lsum, o, 64);
    if (lane == 0) sRed[w] = (double)lsum;
    __syncthreads();
    if (tid == 0)
        recon_part[blockIdx.x] = sRed[0] + sRed[1] + sRed[2] + sRed[3];
}

// ---------------- K10: final reduction over partial arrays ----------------
__global__ __launch_bounds__(1024) void k_final(const double* __restrict__ kl_part,
                                                const double* __restrict__ recon_part,
                                                float* __restrict__ out) {
    __shared__ double sK[16], sR[16];
    const int tid = threadIdx.x, lane = tid & 63, wid = tid >> 6;
    double kl = 0.0, rc = 0.0;
    for (int i = tid; i < 5000; i += 1024) kl += kl_part[i];
    for (int i = tid; i < EMLP_BLOCKS; i += 1024) rc += recon_part[i];
    for (int o = 32; o > 0; o >>= 1) {
        kl += __shfl_xor(kl, o, 64);
        rc += __shfl_xor(rc, o, 64);
    }
    if (lane == 0) { sK[wid] = kl; sR[wid] = rc; }
    __syncthreads();
    if (tid == 0) {
        double K = 0.0, R = 0.0;
        for (int i = 0; i < 16; ++i) { K += sK[i]; R += sR[i]; }
        const double recon = -R / (double)ETOT;
        const double klv = -0.5 * K / ((double)N_NODES * 64.0);
        out[0] = (float)(recon + klv);
        out[1] = (float)recon;
        out[2] = (float)klv;
    }
}

extern "C" void kernel_launch(void* const* d_in, const int* in_sizes, int n_in,
                              void* d_out, int out_size, void* d_ws, size_t ws_size,
                              hipStream_t stream) {
    const float* x   = (const float*)d_in[0];
    const float* eps = (const float*)d_in[1];
    const int* EI    = (const int*)d_in[2];
    const int* pos   = (const int*)d_in[3];
    const int* neg   = (const int*)d_in[4];
    const float* W1  = (const float*)d_in[5];
    const float* b1  = (const float*)d_in[6];
    const float* g1  = (const float*)d_in[7];
    const float* bt1 = (const float*)d_in[8];
    const float* Wmu = (const float*)d_in[9];
    const float* bmu = (const float*)d_in[10];
    const float* Wlv = (const float*)d_in[11];
    const float* blv = (const float*)d_in[12];
    const float* Wd1 = (const float*)d_in[13];
    const float* bd1 = (const float*)d_in[14];
    const float* Wd2 = (const float*)d_in[15];
    const float* bd2 = (const float*)d_in[16];
    const float* Wa  = (const float*)d_in[17];
    const float* ba  = (const float*)d_in[18];
    const float* Wb  = (const float*)d_in[19];
    const float* bb  = (const float*)d_in[20];
    const float* tau = (const float*)d_in[21];

    const int* e_src = EI;
    const int* e_dst = EI + E2;
    const int* ps = pos;
    const int* pd = pos + EP;

    float* ws = (float*)d_ws;
    unsigned short* m1bf  = (unsigned short*)ws;            // [20000,256] bf16 (A)
    unsigned short* hmlbf = (unsigned short*)ws;            // [20000,128] bf16 (A, after m1)
    unsigned short* hdec  = (unsigned short*)(ws + 2560000);// [20000,64] bf16 (A)
    unsigned short* h2bf = (unsigned short*)(ws + 3840000); // [20000,64] bf16
    unsigned short* h1bf = (unsigned short*)(ws + 5120000); // [20000,256] bf16 (B)
    unsigned short* z    = (unsigned short*)(ws + 10240000);// [20000,64] bf16
    float* dis   = ws + 11520000;             // [20000]
    unsigned short* WaT = (unsigned short*)(ws + 11540004); // [64,256] bf16
    int* cntA = (int*)(ws + 11548200);
    int* rsA  = (int*)(ws + 11568200);
    int* adjA = (int*)(ws + 11588204);
    int* cntP = (int*)(ws + 11828204);
    int* rsP  = (int*)(ws + 11848204);
    int* adjP = (int*)(ws + 11868208);
    int2* uv  = (int2*)(ws + 11988208);       // [720000] int2
    double* kl_part    = (double*)(ws + 13428208); // [5000]
    double* recon_part = (double*)(ws + 13438208); // [1024] -> ends 13440256
    unsigned short* W1T  = (unsigned short*)(ws + 13440256); // [256,256] bf16
    unsigned short* WmlT = (unsigned short*)(ws + 13473024); // [128,256] bf16

    hipMemsetAsync(cntA, 0, N_NODES * 4, stream);
    hipMemsetAsync(cntP, 0, N_NODES * 4, stream);

    // prep + CSR (3 launches)
    k_prep_csr<<<WA_B + W1T_B + WML_B + UV_B + HA_B + HP_B, 256, 0, stream>>>(
        Wa, WaT, W1, W1T, Wmu, Wlv, WmlT, pos, neg, uv, e_dst, cntA, pd, cntP);
    k_scan2<<<2, 1024, 0, stream>>>(cntA, rsA, cntP, rsP);
    k_finish_csr<<<FA_B + FP_B + DIS_B, 256, 0, stream>>>(
        e_src, e_dst, cntA, adjA, ps, pd, cntP, adjP, rsP, dis);

    // encoder (MFMA GEMMs + gathers)
    k_mm_xW1_mfma<<<2500, 256, 0, stream>>>(x, W1T, m1bf);
    k_gather_ln<<<5000, 256, 0, stream>>>(m1bf, rsA, adjA, b1, g1, bt1, h1bf);
    k_mm_hml_mfma<<<1250, 256, 0, stream>>>(h1bf, WmlT, hmlbf);
    k_gather_mulv<<<5000, 256, 0, stream>>>(hmlbf, rsA, adjA, bmu, blv, eps, z, kl_part);

    // decoder (bf16 intermediates)
    k_dec_fused<unsigned short, unsigned short><<<5000, 256, 0, stream>>>(
        z, rsP, adjP, dis, Wd1, bd1, hdec);
    k_dec_fused<unsigned short, unsigned short><<<5000, 256, 0, stream>>>(
        hdec, rsP, adjP, dis, Wd2, bd2, h2bf);

    // edge MLP + loss
    k_edge_mlp_mfma<<<EMLP_BLOCKS, 256, 0, stream>>>(h2bf, uv, WaT, ba, Wb, bb, tau, recon_part);
    k_final<<<1, 1024, 0, stream>>>(kl_part, recon_part, (float*)d_out);
}

// Round 13
// 339.870 us; speedup vs baseline: 1.0535x; 1.0535x over previous
//
#include <hip/hip_runtime.h>
#include <hip/hip_bf16.h>
#include <math.h>

#define N_NODES 20000
#define E2      240000     // directed edges (2E)
#define EP      120000     // positive edges
#define ENEG    600000     // negative edges
#define ETOT    720000     // EP + ENEG
#define NTILE   11250      // ETOT / 64
#define EMLP_BLOCKS 1024   // persistent: 4 blocks/CU

// merged-kernel block ranges
#define WA_B  64
#define W1T_B 256
#define WML_B 128
#define UV_B  2813
#define HA_B  938
#define HP_B  469
#define FA_B  938
#define FP_B  469
#define DIS_B 79

typedef __attribute__((ext_vector_type(8))) short bf16x8;
typedef __attribute__((ext_vector_type(4))) float f32x4;

__device__ __forceinline__ float logsigf(float x) {
    return fminf(x, 0.0f) - log1pf(expf(-fabsf(x)));
}

__device__ __forceinline__ unsigned short f2bf(float f) {
    unsigned u = __float_as_uint(f);
    u += 0x7FFF + ((u >> 16) & 1);   // RNE
    return (unsigned short)(u >> 16);
}

__device__ __forceinline__ float bflo(unsigned u) { return __uint_as_float(u << 16); }
__device__ __forceinline__ float bfhi(unsigned u) { return __uint_as_float(u & 0xFFFF0000u); }

__device__ __forceinline__ void store_out(float v, float* p) { *p = v; }
__device__ __forceinline__ void store_out(float v, unsigned short* p) { *p = f2bf(v); }
__device__ __forceinline__ float load_in(const float* p) { return *p; }
__device__ __forceinline__ float load_in(const unsigned short* p) {
    return __uint_as_float(((unsigned)*p) << 16);
}

// pack 2 dims of hu/hv into k'-layout: [u(d0)|v(d0), bf2(ad0,pr0), u(d1)|v(d1), bf2(ad1,pr1)]
__device__ __forceinline__ int4 pack_phi(unsigned hu, unsigned hv) {
    const float fu0 = __uint_as_float(hu << 16);
    const float fu1 = __uint_as_float(hu & 0xFFFF0000u);
    const float fv0 = __uint_as_float(hv << 16);
    const float fv1 = __uint_as_float(hv & 0xFFFF0000u);
    const float ad0 = fabsf(fu0 - fv0), ad1 = fabsf(fu1 - fv1);
    const float pr0 = fu0 * fv0,        pr1 = fu1 * fv1;
    union { __hip_bfloat162 h; int u; } c0, c1;
    c0.h = __float22bfloat162_rn(float2{ad0, pr0});
    c1.h = __float22bfloat162_rn(float2{ad1, pr1});
    int4 r;
    r.x = (int)((hu & 0xFFFFu) | (hv << 16));
    r.y = c0.u;
    r.z = (int)((hu >> 16) | (hv & 0xFFFF0000u));
    r.w = c1.u;
    return r;
}

// --- merged prep: WaT + W1T + WmlT permutes, uv build, both CSR histograms ---
__global__ void k_prep_csr(const float* __restrict__ Wa, unsigned short* __restrict__ WaT,
                           const float* __restrict__ W1, unsigned short* __restrict__ W1T,
                           const float* __restrict__ Wmu, const float* __restrict__ Wlv,
                           unsigned short* __restrict__ WmlT,
                           const int* __restrict__ pos, const int* __restrict__ neg,
                           int2* __restrict__ uv,
                           const int* __restrict__ e_dst, int* __restrict__ cntA,
                           const int* __restrict__ pd, int* __restrict__ cntP) {
    const int b = blockIdx.x, tid = threadIdx.x;
    if (b < WA_B) {
        const int idx = b * 256 + tid;
        const int n = idx >> 8, kp = idx & 255;
        const int d = kp >> 2, part = kp & 3;
        WaT[idx] = f2bf(Wa[(part * 64 + d) * 64 + n]);
    } else if (b < WA_B + W1T_B) {
        const int idx = (b - WA_B) * 256 + tid;            // 0..65535
        const int n = idx >> 8, k = idx & 255;
        W1T[idx] = f2bf(W1[k * 256 + n]);
    } else if (b < WA_B + W1T_B + WML_B) {
        const int idx = (b - WA_B - W1T_B) * 256 + tid;    // 0..32767
        const int n = idx >> 8, k = idx & 255;             // n: interleaved col
        const float* W = (n & 1) ? Wlv : Wmu;
        WmlT[idx] = f2bf(W[k * 64 + (n >> 1)]);
    } else if (b < WA_B + W1T_B + WML_B + UV_B) {
        const int j = (b - WA_B - W1T_B - WML_B) * 256 + tid;
        if (j < ETOT) {
            int u, v;
            if (j < EP) { u = pos[j]; v = pos[EP + j]; }
            else        { u = neg[j - EP]; v = neg[ENEG + (j - EP)]; }
            uv[j] = make_int2(u, v);
        }
    } else if (b < WA_B + W1T_B + WML_B + UV_B + HA_B) {
        const int e = (b - WA_B - W1T_B - WML_B - UV_B) * 256 + tid;
        if (e < E2) atomicAdd(&cntA[e_dst[e]], 1);
    } else {
        const int e = (b - WA_B - W1T_B - WML_B - UV_B - HA_B) * 256 + tid;
        if (e < EP) atomicAdd(&cntP[pd[e]], 1);
    }
}

// ---- both exclusive scans in one launch: block 0 -> graph A, block 1 -> P ----
__global__ __launch_bounds__(1024) void k_scan2(int* __restrict__ cntA, int* __restrict__ rsA,
                                                int* __restrict__ cntP, int* __restrict__ rsP) {
    int* cnt = blockIdx.x ? cntP : cntA;
    int* rs  = blockIdx.x ? rsP  : rsA;
    int* cur = cnt;   // cursor aliases cnt (read-before-overwrite)
    const int n = N_NODES;
    __shared__ int wexc[16];
    __shared__ int s_carry, s_tot;
    const int tid = threadIdx.x, lane = tid & 63, wid = tid >> 6;
    if (tid == 0) s_carry = 0;
    __syncthreads();
    for (int base = 0; base < n; base += 1024) {
        const int i = base + tid;
        const int v = (i < n) ? cnt[i] : 0;
        int x = v;
#pragma unroll
        for (int d = 1; d < 64; d <<= 1) {
            const int t = __shfl_up(x, d, 64);
            if (lane >= d) x += t;
        }
        if (lane == 63) wexc[wid] = x;
        __syncthreads();
        if (tid == 0) {
            int a = 0;
#pragma unroll
            for (int k = 0; k < 16; ++k) { const int t = wexc[k]; wexc[k] = a; a += t; }
            s_tot = a;
        }
        __syncthreads();
        const int excl = s_carry + wexc[wid] + x - v;
        if (i < n) { rs[i] = excl; cur[i] = excl; }
        __syncthreads();
        if (tid == 0) s_carry += s_tot;
        __syncthreads();
    }
    if (tid == 0) rs[n] = s_carry;
}

// ---- merged finish: fill both adjacency lists + dis ----
__global__ void k_finish_csr(const int* __restrict__ e_src, const int* __restrict__ e_dst,
                             int* __restrict__ curA, int* __restrict__ adjA,
                             const int* __restrict__ ps, const int* __restrict__ pd,
                             int* __restrict__ curP, int* __restrict__ adjP,
                             const int* __restrict__ rsP, float* __restrict__ dis) {
    const int b = blockIdx.x, tid = threadIdx.x;
    if (b < FA_B) {
        const int e = b * 256 + tid;
        if (e < E2) {
            const int p = atomicAdd(&curA[e_dst[e]], 1);
            adjA[p] = e_src[e];
        }
    } else if (b < FA_B + FP_B) {
        const int e = (b - FA_B) * 256 + tid;
        if (e < EP) {
            const int p = atomicAdd(&curP[pd[e]], 1);
            adjP[p] = ps[e];
        }
    } else {
        const int i = (b - FA_B - FP_B) * 256 + tid;
        if (i < N_NODES) dis[i] = rsqrtf((float)(rsP[i + 1] - rsP[i] + 1));
    }
}

// ---- K1: m1bf = bf16(x @ W1) via MFMA. grid 625x4: 32-row M x 64-col N ----
__global__ __launch_bounds__(256) void k_mm_xW1_mfma(const float* __restrict__ x,
                                                     const unsigned short* __restrict__ W1T,
                                                     unsigned short* __restrict__ m1) {
    __shared__ unsigned short sA[32 * 264];   // 16896 B
    const int tid = threadIdx.x;
    const int w = tid >> 6, lane = tid & 63;
    const int l15 = lane & 15, quad = lane >> 4;
    const int mb = blockIdx.x >> 2, nb = blockIdx.x & 3;

    // stage A: 32 rows x 256 k, fp32 -> bf16
    for (int i = tid; i < 2048; i += 256) {
        const int row = i >> 6, kc = (i & 63) << 2;
        const float4 xv = *(const float4*)&x[((long)mb * 32 + row) * 256 + kc];
        union { unsigned short s[4]; unsigned long long ll; } pk;
        pk.s[0] = f2bf(xv.x); pk.s[1] = f2bf(xv.y);
        pk.s[2] = f2bf(xv.z); pk.s[3] = f2bf(xv.w);
        *(unsigned long long*)&sA[row * 264 + kc] = pk.ll;
    }

    bf16x8 breg[8];
#pragma unroll
    for (int ks = 0; ks < 8; ++ks)
        breg[ks] = *(const bf16x8*)&W1T[((nb * 64 + w * 16 + l15) << 8) + ks * 32 + quad * 8];
    __syncthreads();

    f32x4 acc[2];
    acc[0] = (f32x4){0.f,0.f,0.f,0.f};
    acc[1] = (f32x4){0.f,0.f,0.f,0.f};
#pragma unroll
    for (int ks = 0; ks < 8; ++ks) {
#pragma unroll
        for (int st = 0; st < 2; ++st) {
            const bf16x8 af = *(const bf16x8*)&sA[(st * 16 + l15) * 264 + ks * 32 + quad * 8];
            acc[st] = __builtin_amdgcn_mfma_f32_16x16x32_bf16(af, breg[ks], acc[st], 0, 0, 0);
        }
    }
    // D: row = quad*4+r (x-row), col = l15 (n)
#pragma unroll
    for (int st = 0; st < 2; ++st)
#pragma unroll
        for (int r = 0; r < 4; ++r)
            m1[((long)mb * 32 + st * 16 + quad * 4 + r) * 256 + nb * 64 + w * 16 + l15] =
                f2bf(acc[st][r]);
}

// ---- K2: h1bf = bf16(relu(LN(segsum(m1bf[adj]) + b1))); 4-way MLP gather ----
__global__ __launch_bounds__(256) void k_gather_ln(const unsigned short* __restrict__ m1,
                                                   const int* __restrict__ rs,
                                                   const int* __restrict__ adj,
                                                   const float* __restrict__ b1,
                                                   const float* __restrict__ g1,
                                                   const float* __restrict__ bt1,
                                                   unsigned short* __restrict__ h1) {
    const int wid = threadIdx.x >> 6, lane = threadIdx.x & 63;
    const int n = blockIdx.x * 4 + wid;
    const int beg = rs[n], end = rs[n + 1];
    float4 a0 = {0.f,0.f,0.f,0.f}, a1 = {0.f,0.f,0.f,0.f};
    float4 a2 = {0.f,0.f,0.f,0.f}, a3 = {0.f,0.f,0.f,0.f};
    int j = beg;
    for (; j + 3 < end; j += 4) {
        const int s0 = adj[j], s1 = adj[j + 1], s2 = adj[j + 2], s3 = adj[j + 3];
        const uint2 u0 = *(const uint2*)(m1 + (long)s0 * 256 + lane * 4);
        const uint2 u1 = *(const uint2*)(m1 + (long)s1 * 256 + lane * 4);
        const uint2 u2 = *(const uint2*)(m1 + (long)s2 * 256 + lane * 4);
        const uint2 u3 = *(const uint2*)(m1 + (long)s3 * 256 + lane * 4);
        a0.x += bflo(u0.x); a0.y += bfhi(u0.x); a0.z += bflo(u0.y); a0.w += bfhi(u0.y);
        a1.x += bflo(u1.x); a1.y += bfhi(u1.x); a1.z += bflo(u1.y); a1.w += bfhi(u1.y);
        a2.x += bflo(u2.x); a2.y += bfhi(u2.x); a2.z += bflo(u2.y); a2.w += bfhi(u2.y);
        a3.x += bflo(u3.x); a3.y += bfhi(u3.x); a3.z += bflo(u3.y); a3.w += bfhi(u3.y);
    }
    for (; j < end; ++j) {
        const int s0 = adj[j];
        const uint2 u = *(const uint2*)(m1 + (long)s0 * 256 + lane * 4);
        a0.x += bflo(u.x); a0.y += bfhi(u.x); a0.z += bflo(u.y); a0.w += bfhi(u.y);
    }
    float4 v;
    const float4 b = *(const float4*)(b1 + lane * 4);
    v.x = (a0.x + a1.x) + (a2.x + a3.x) + b.x;
    v.y = (a0.y + a1.y) + (a2.y + a3.y) + b.y;
    v.z = (a0.z + a1.z) + (a2.z + a3.z) + b.z;
    v.w = (a0.w + a1.w) + (a2.w + a3.w) + b.w;
    float s  = v.x + v.y + v.z + v.w;
    float sq = v.x * v.x + v.y * v.y + v.z * v.z + v.w * v.w;
    for (int o = 32; o > 0; o >>= 1) {
        s  += __shfl_xor(s, o, 64);
        sq += __shfl_xor(sq, o, 64);
    }
    const float mean = s * (1.0f / 256.0f);
    const float var  = sq * (1.0f / 256.0f) - mean * mean;
    const float rsv = rsqrtf(var + 1e-5f);
    const float4 g  = *(const float4*)(g1 + lane * 4);
    const float4 bt = *(const float4*)(bt1 + lane * 4);
    union { unsigned short sh[4]; unsigned long long ll; } pk;
    pk.sh[0] = f2bf(fmaxf((v.x - mean) * rsv * g.x + bt.x, 0.f));
    pk.sh[1] = f2bf(fmaxf((v.y - mean) * rsv * g.y + bt.y, 0.f));
    pk.sh[2] = f2bf(fmaxf((v.z - mean) * rsv * g.z + bt.z, 0.f));
    pk.sh[3] = f2bf(fmaxf((v.w - mean) * rsv * g.w + bt.w, 0.f));
    *(unsigned long long*)&h1[(long)n * 256 + lane * 4] = pk.ll;
}

// ---- K3: hmlbf = bf16(h1bf @ [Wmu|Wlv] interleaved) via MFMA. grid 625x2 ----
__global__ __launch_bounds__(256) void k_mm_hml_mfma(const unsigned short* __restrict__ h1,
                                                     const unsigned short* __restrict__ WmlT,
                                                     unsigned short* __restrict__ hml) {
    __shared__ unsigned short sA[32 * 264];
    const int tid = threadIdx.x;
    const int w = tid >> 6, lane = tid & 63;
    const int l15 = lane & 15, quad = lane >> 4;
    const int mb = blockIdx.x >> 1, nb = blockIdx.x & 1;

    // stage A: 32 rows x 32 chunks of 8 shorts (full 256-k rows)
    for (int i = tid; i < 1024; i += 256) {
        const int row = i >> 5, kc = (i & 31) << 3;
        *(int4*)&sA[row * 264 + kc] = *(const int4*)&h1[((long)mb * 32 + row) * 256 + kc];
    }

    bf16x8 breg[8];
#pragma unroll
    for (int ks = 0; ks < 8; ++ks)
        breg[ks] = *(const bf16x8*)&WmlT[((nb * 64 + w * 16 + l15) << 8) + ks * 32 + quad * 8];
    __syncthreads();

    f32x4 acc[2];
    acc[0] = (f32x4){0.f,0.f,0.f,0.f};
    acc[1] = (f32x4){0.f,0.f,0.f,0.f};
#pragma unroll
    for (int ks = 0; ks < 8; ++ks) {
#pragma unroll
        for (int st = 0; st < 2; ++st) {
            const bf16x8 af = *(const bf16x8*)&sA[(st * 16 + l15) * 264 + ks * 32 + quad * 8];
            acc[st] = __builtin_amdgcn_mfma_f32_16x16x32_bf16(af, breg[ks], acc[st], 0, 0, 0);
        }
    }
#pragma unroll
    for (int st = 0; st < 2; ++st)
#pragma unroll
        for (int r = 0; r < 4; ++r)
            hml[((long)mb * 32 + st * 16 + quad * 4 + r) * 128 + nb * 64 + w * 16 + l15] =
                f2bf(acc[st][r]);
}

// ---- K4: gather hmlbf (interleaved mu/lv) + z (bf16); 4-way MLP gather ----
__global__ __launch_bounds__(256) void k_gather_mulv(const unsigned short* __restrict__ hml,
                                                     const int* __restrict__ rs,
                                                     const int* __restrict__ adj,
                                                     const float* __restrict__ bmu,
                                                     const float* __restrict__ blv,
                                                     const float* __restrict__ eps,
                                                     unsigned short* __restrict__ z,
                                                     double* __restrict__ kl_part) {
    __shared__ double sKL[4];
    const int wid = threadIdx.x >> 6, lane = threadIdx.x & 63;
    const int n = blockIdx.x * 4 + wid;
    const int beg = rs[n], end = rs[n + 1];
    float m0 = 0.f, m1_ = 0.f, m2 = 0.f, m3 = 0.f;
    float l0 = 0.f, l1 = 0.f, l2 = 0.f, l3 = 0.f;
    int j = beg;
    for (; j + 3 < end; j += 4) {
        const int s0 = adj[j], s1 = adj[j + 1], s2 = adj[j + 2], s3 = adj[j + 3];
        const unsigned u0 = *(const unsigned*)(hml + (long)s0 * 128 + lane * 2);
        const unsigned u1 = *(const unsigned*)(hml + (long)s1 * 128 + lane * 2);
        const unsigned u2 = *(const unsigned*)(hml + (long)s2 * 128 + lane * 2);
        const unsigned u3 = *(const unsigned*)(hml + (long)s3 * 128 + lane * 2);
        m0 += bflo(u0); l0 += bfhi(u0);
        m1_ += bflo(u1); l1 += bfhi(u1);
        m2 += bflo(u2); l2 += bfhi(u2);
        m3 += bflo(u3); l3 += bfhi(u3);
    }
    for (; j < end; ++j) {
        const int s0 = adj[j];
        const unsigned u0 = *(const unsigned*)(hml + (long)s0 * 128 + lane * 2);
        m0 += bflo(u0); l0 += bfhi(u0);
    }
    const float mu = (m0 + m1_) + (m2 + m3) + bmu[lane];
    const float lv = (l0 + l1) + (l2 + l3) + blv[lane];
    z[(long)n * 64 + lane] = f2bf(mu + eps[(long)n * 64 + lane] * expf(0.5f * lv));
    float term = 1.0f + lv - mu * mu - expf(lv);
    for (int o = 32; o > 0; o >>= 1) term += __shfl_xor(term, o, 64);
    if (lane == 0) sKL[wid] = (double)term;
    __syncthreads();
    if (threadIdx.x == 0)
        kl_part[blockIdx.x] = sKL[0] + sKL[1] + sKL[2] + sKL[3];
}

// ---- K5/K6: fused decoder layer: 4-way gather_norm + 64x64 matmul + relu ----
template <typename IN, typename OUT>
__global__ __launch_bounds__(256) void k_dec_fused(const IN* __restrict__ feat,
                                                   const int* __restrict__ rs,
                                                   const int* __restrict__ adj,
                                                   const float* __restrict__ dis,
                                                   const float* __restrict__ Wd,
                                                   const float* __restrict__ bd,
                                                   OUT* __restrict__ out) {
    __shared__ float sW[64 * 64];
    __shared__ float rows[4][64];
    const int tid = threadIdx.x;
    {
        const float4* w4 = (const float4*)Wd;
        float4* sw4 = (float4*)sW;
        for (int i = tid; i < 1024; i += 256) sw4[i] = w4[i];
    }
    const int wid = tid >> 6, lane = tid & 63;
    const int n = blockIdx.x * 4 + wid;
    const int beg = rs[n], end = rs[n + 1];
    float a0 = 0.f, a1 = 0.f, a2 = 0.f, a3 = 0.f;
    int j = beg;
    for (; j + 3 < end; j += 4) {
        const int s0 = adj[j], s1 = adj[j + 1], s2 = adj[j + 2], s3 = adj[j + 3];
        a0 += load_in(&feat[(long)s0 * 64 + lane]) * dis[s0];
        a1 += load_in(&feat[(long)s1 * 64 + lane]) * dis[s1];
        a2 += load_in(&feat[(long)s2 * 64 + lane]) * dis[s2];
        a3 += load_in(&feat[(long)s3 * 64 + lane]) * dis[s3];
    }
    for (; j < end; ++j) {
        const int s0 = adj[j];
        a0 += load_in(&feat[(long)s0 * 64 + lane]) * dis[s0];
    }
    const float dn = dis[n];
    rows[wid][lane] = ((a0 + a1) + (a2 + a3)) * dn
                    + load_in(&feat[(long)n * 64 + lane]) * dn * dn;
    __syncthreads();
    float acc = 0.f;
    for (int k = 0; k < 64; k += 4) {
        const float4 a = *(const float4*)&rows[wid][k];
        acc += a.x * sW[(k+0)*64+lane] + a.y * sW[(k+1)*64+lane]
             + a.z * sW[(k+2)*64+lane] + a.w * sW[(k+3)*64+lane];
    }
    store_out(fmaxf(acc + bd[lane], 0.f), &out[(long)n * 64 + lane]);
}

// ---------------- K9: edge MLP, persistent MFMA, transposed D (R11 exact) ----
__global__ __launch_bounds__(256, 4) void k_edge_mlp_mfma(
        const unsigned short* __restrict__ h2bf,
        const int2* __restrict__ uv,
        const unsigned short* __restrict__ WaT,
        const float* __restrict__ ba,
        const float* __restrict__ Wb,
        const float* __restrict__ bb,
        const float* __restrict__ tau,
        double* __restrict__ recon_part) {
    __shared__ unsigned short sPhi[64 * 264];  // 33792 B
    __shared__ float sEp[256];
    __shared__ double sRed[4];
    const int tid = threadIdx.x;
    const int w = tid >> 6, lane = tid & 63;
    const int l15 = lane & 15, quad = lane >> 4;
    const int ge = lane >> 3;
    const int c  = lane & 7;

    bf16x8 breg[8];
#pragma unroll
    for (int ks = 0; ks < 8; ++ks)
        breg[ks] = *(const bf16x8*)&WaT[(w * 16 + l15) * 256 + ks * 32 + quad * 8];

    const float4 ba4 = *(const float4*)&ba[w * 16 + quad * 4];
    const float4 wb4 = *(const float4*)&Wb[w * 16 + quad * 4];
    const float bb0 = bb[0];
    const float itau = 1.0f / fmaxf(tau[0], 1e-4f);

    float lsum = 0.f;

    int t = blockIdx.x;
    int2 uv0 = uv[(long)t * 64 + w * 16 + ge];
    int2 uv1 = uv[(long)t * 64 + w * 16 + 8 + ge];
    int4 hu0 = *(const int4*)&h2bf[(long)uv0.x * 64 + c * 8];
    int4 hv0 = *(const int4*)&h2bf[(long)uv0.y * 64 + c * 8];
    int4 hu1 = *(const int4*)&h2bf[(long)uv1.x * 64 + c * 8];
    int4 hv1 = *(const int4*)&h2bf[(long)uv1.y * 64 + c * 8];

    for (; t < NTILE; t += EMLP_BLOCKS) {
        {
            unsigned short* d0 = &sPhi[(w * 16 + ge) * 264 + c * 32];
            *(int4*)(d0 +  0) = pack_phi((unsigned)hu0.x, (unsigned)hv0.x);
            *(int4*)(d0 +  8) = pack_phi((unsigned)hu0.y, (unsigned)hv0.y);
            *(int4*)(d0 + 16) = pack_phi((unsigned)hu0.z, (unsigned)hv0.z);
            *(int4*)(d0 + 24) = pack_phi((unsigned)hu0.w, (unsigned)hv0.w);
            unsigned short* d1 = &sPhi[(w * 16 + 8 + ge) * 264 + c * 32];
            *(int4*)(d1 +  0) = pack_phi((unsigned)hu1.x, (unsigned)hv1.x);
            *(int4*)(d1 +  8) = pack_phi((unsigned)hu1.y, (unsigned)hv1.y);
            *(int4*)(d1 + 16) = pack_phi((unsigned)hu1.z, (unsigned)hv1.z);
            *(int4*)(d1 + 24) = pack_phi((unsigned)hu1.w, (unsigned)hv1.w);
        }
        __syncthreads();

        const int tn = t + EMLP_BLOCKS;
        if (tn < NTILE) {
            uv0 = uv[(long)tn * 64 + w * 16 + ge];
            uv1 = uv[(long)tn * 64 + w * 16 + 8 + ge];
            hu0 = *(const int4*)&h2bf[(long)uv0.x * 64 + c * 8];
            hv0 = *(const int4*)&h2bf[(long)uv0.y * 64 + c * 8];
            hu1 = *(const int4*)&h2bf[(long)uv1.x * 64 + c * 8];
            hv1 = *(const int4*)&h2bf[(long)uv1.y * 64 + c * 8];
        }

        f32x4 acc[4];
#pragma unroll
        for (int mt = 0; mt < 4; ++mt) acc[mt] = (f32x4){0.f, 0.f, 0.f, 0.f};
#pragma unroll
        for (int ks = 0; ks < 8; ++ks) {
#pragma unroll
            for (int mt = 0; mt < 4; ++mt) {
                const bf16x8 bf = *(const bf16x8*)&sPhi[(mt * 16 + l15) * 264 +
                                                        ks * 32 + quad * 8];
                acc[mt] = __builtin_amdgcn_mfma_f32_16x16x32_bf16(breg[ks], bf, acc[mt], 0, 0, 0);
            }
        }

        float sv[4];
#pragma unroll
        for (int mt = 0; mt < 4; ++mt) {
            float s = fmaxf(acc[mt][0] + ba4.x, 0.f) * wb4.x
                    + fmaxf(acc[mt][1] + ba4.y, 0.f) * wb4.y
                    + fmaxf(acc[mt][2] + ba4.z, 0.f) * wb4.z
                    + fmaxf(acc[mt][3] + ba4.w, 0.f) * wb4.w;
            s += __shfl_xor(s, 16, 64);
            s += __shfl_xor(s, 32, 64);
            sv[mt] = s;
        }
        const float ssel = (quad == 0) ? sv[0] : (quad == 1) ? sv[1]
                         : (quad == 2) ? sv[2] : sv[3];
        sEp[(w << 6) + lane] = ssel;
        __syncthreads();

        if (lane < 16) {
            const int et = (w << 4) + lane;
            const float s_e = sEp[et] + sEp[64 + et] + sEp[128 + et] + sEp[192 + et];
            const long j = (long)t * 64 + et;
            const float logit = (s_e + bb0) * itau;
            lsum += (j < EP) ? 5.0f * logsigf(logit) : logsigf(-logit);
        }
    }

    for (int o = 32; o > 0; o >>= 1) lsum += __shfl_xor(lsum, o, 64);
    if (lane == 0) sRed[w] = (double)lsum;
    __syncthreads();
    if (tid == 0)
        recon_part[blockIdx.x] = sRed[0] + sRed[1] + sRed[2] + sRed[3];
}

// ---------------- K10: final reduction over partial arrays ----------------
__global__ __launch_bounds__(1024) void k_final(const double* __restrict__ kl_part,
                                                const double* __restrict__ recon_part,
                                                float* __restrict__ out) {
    __shared__ double sK[16], sR[16];
    const int tid = threadIdx.x, lane = tid & 63, wid = tid >> 6;
    double kl = 0.0, rc = 0.0;
    for (int i = tid; i < 5000; i += 1024) kl += kl_part[i];
    for (int i = tid; i < EMLP_BLOCKS; i += 1024) rc += recon_part[i];
    for (int o = 32; o > 0; o >>= 1) {
        kl += __shfl_xor(kl, o, 64);
        rc += __shfl_xor(rc, o, 64);
    }
    if (lane == 0) { sK[wid] = kl; sR[wid] = rc; }
    __syncthreads();
    if (tid == 0) {
        double K = 0.0, R = 0.0;
        for (int i = 0; i < 16; ++i) { K += sK[i]; R += sR[i]; }
        const double recon = -R / (double)ETOT;
        const double klv = -0.5 * K / ((double)N_NODES * 64.0);
        out[0] = (float)(recon + klv);
        out[1] = (float)recon;
        out[2] = (float)klv;
    }
}

extern "C" void kernel_launch(void* const* d_in, const int* in_sizes, int n_in,
                              void* d_out, int out_size, void* d_ws, size_t ws_size,
                              hipStream_t stream) {
    const float* x   = (const float*)d_in[0];
    const float* eps = (const float*)d_in[1];
    const int* EI    = (const int*)d_in[2];
    const int* pos   = (const int*)d_in[3];
    const int* neg   = (const int*)d_in[4];
    const float* W1  = (const float*)d_in[5];
    const float* b1  = (const float*)d_in[6];
    const float* g1  = (const float*)d_in[7];
    const float* bt1 = (const float*)d_in[8];
    const float* Wmu = (const float*)d_in[9];
    const float* bmu = (const float*)d_in[10];
    const float* Wlv = (const float*)d_in[11];
    const float* blv = (const float*)d_in[12];
    const float* Wd1 = (const float*)d_in[13];
    const float* bd1 = (const float*)d_in[14];
    const float* Wd2 = (const float*)d_in[15];
    const float* bd2 = (const float*)d_in[16];
    const float* Wa  = (const float*)d_in[17];
    const float* ba  = (const float*)d_in[18];
    const float* Wb  = (const float*)d_in[19];
    const float* bb  = (const float*)d_in[20];
    const float* tau = (const float*)d_in[21];

    const int* e_src = EI;
    const int* e_dst = EI + E2;
    const int* ps = pos;
    const int* pd = pos + EP;

    float* ws = (float*)d_ws;
    unsigned short* m1bf  = (unsigned short*)ws;            // [20000,256] bf16 (A)
    unsigned short* hmlbf = (unsigned short*)ws;            // [20000,128] bf16 (A, after m1)
    unsigned short* hdec  = (unsigned short*)(ws + 2560000);// [20000,64] bf16 (A)
    unsigned short* h2bf = (unsigned short*)(ws + 3840000); // [20000,64] bf16
    unsigned short* h1bf = (unsigned short*)(ws + 5120000); // [20000,256] bf16 (B)
    unsigned short* z    = (unsigned short*)(ws + 10240000);// [20000,64] bf16
    float* dis   = ws + 11520000;             // [20000]
    unsigned short* WaT = (unsigned short*)(ws + 11540004); // [64,256] bf16
    int* cntA = (int*)(ws + 11548200);
    int* rsA  = (int*)(ws + 11568200);
    int* adjA = (int*)(ws + 11588204);
    int* cntP = (int*)(ws + 11828204);
    int* rsP  = (int*)(ws + 11848204);
    int* adjP = (int*)(ws + 11868208);
    int2* uv  = (int2*)(ws + 11988208);       // [720000] int2
    double* kl_part    = (double*)(ws + 13428208); // [5000]
    double* recon_part = (double*)(ws + 13438208); // [1024] -> ends 13440256
    unsigned short* W1T  = (unsigned short*)(ws + 13440256); // [256,256] bf16
    unsigned short* WmlT = (unsigned short*)(ws + 13473024); // [128,256] bf16

    hipMemsetAsync(cntA, 0, N_NODES * 4, stream);
    hipMemsetAsync(cntP, 0, N_NODES * 4, stream);

    // prep + CSR (3 launches)
    k_prep_csr<<<WA_B + W1T_B + WML_B + UV_B + HA_B + HP_B, 256, 0, stream>>>(
        Wa, WaT, W1, W1T, Wmu, Wlv, WmlT, pos, neg, uv, e_dst, cntA, pd, cntP);
    k_scan2<<<2, 1024, 0, stream>>>(cntA, rsA, cntP, rsP);
    k_finish_csr<<<FA_B + FP_B + DIS_B, 256, 0, stream>>>(
        e_src, e_dst, cntA, adjA, ps, pd, cntP, adjP, rsP, dis);

    // encoder (MFMA GEMMs + 4-way gathers)
    k_mm_xW1_mfma<<<2500, 256, 0, stream>>>(x, W1T, m1bf);
    k_gather_ln<<<5000, 256, 0, stream>>>(m1bf, rsA, adjA, b1, g1, bt1, h1bf);
    k_mm_hml_mfma<<<1250, 256, 0, stream>>>(h1bf, WmlT, hmlbf);
    k_gather_mulv<<<5000, 256, 0, stream>>>(hmlbf, rsA, adjA, bmu, blv, eps, z, kl_part);

    // decoder (bf16 intermediates, 4-way gathers)
    k_dec_fused<unsigned short, unsigned short><<<5000, 256, 0, stream>>>(
        z, rsP, adjP, dis, Wd1, bd1, hdec);
    k_dec_fused<unsigned short, unsigned short><<<5000, 256, 0, stream>>>(
        hdec, rsP, adjP, dis, Wd2, bd2, h2bf);

    // edge MLP + loss
    k_edge_mlp_mfma<<<EMLP_BLOCKS, 256, 0, stream>>>(h2bf, uv, WaT, ba, Wb, bb, tau, recon_part);
    k_final<<<1, 1024, 0, stream>>>(kl_part, recon_part, (float*)d_out);
}